// Round 3
// baseline (255.533 us; speedup 1.0000x reference)
//
#include <hip/hip_runtime.h>
#include <hip/hip_bf16.h>

// LocalCorrelation via MFMA pixel-pair dot products, round 3.
// out[b, di*13+dj, h, w] = (1/16) * sum_c zt[b,c,h,w] * zt1[b,c,h+di-6,w+dj-6]
// B=8 C=256 H=W=128, 13x13 taps, zero-padded.
//
// mfma_f32_16x16x32_bf16: M=16 zt pixels (4x4 patch), N=16 zt1 pixels (4x4
// patch), K=32 channels. Block = 8h x 16w p-region, 1024 thr = 16 waves:
// 8 p-patches x 2 waves (each wave owns 8 of the 16 q-patches) -> acc=32 VGPR.
// LDS double-buffered (B 2x44.8KB + A 2x10.2KB = 107.5KB), ONE barrier/chunk:
//   issue loads(k+1) -> MFMA(buf k) -> pack+write(buf k+1) -> barrier.
// Staging: float2 pair loads (pairs share validity since boundaries are even),
// pack to bf16, 2x ds_write_b128 per unit. B-frag reads = one lane base +
// compile-time immediate offsets.

#define CC 256
#define HH 128
#define WW 128
#define NT 169
#define PW 16
#define QWD 28
#define PIXB 80              // bytes per staged pixel row (64 data + 16 pad)
#define NPB 560              // 20*28 q pixels
#define NPA 128              // 8*16 p pixels
#define BBUF (NPB*PIXB)      // 44800
#define ABUF (NPA*PIXB)      // 10240
#define CHPLANE (HH*WW)
#define CHUNK_ADV (32*CHPLANE)   // floats per 32-channel chunk
#define KHALF 85
#define OSTRIDE 132
#define NBU 1120             // B units: 4 octets * 280 pixel-pairs
#define NAU 256              // A units: 4 octets * 64 pixel-pairs

typedef __attribute__((ext_vector_type(8))) short bf16x8;
typedef __attribute__((ext_vector_type(4))) float f32x4;

union SMEM {
    char raw[2*BBUF + 2*ABUF];      // [B0][B1][A0][A1] = 110080 B
    float outb[KHALF*OSTRIDE];      // 44880 B (epilogue alias)
};

static __device__ __forceinline__ unsigned pk2(float a, float b) {
    unsigned x = __bfloat16_as_ushort(__float2bfloat16(a));
    unsigned y = __bfloat16_as_ushort(__float2bfloat16(b));
    return x | (y << 16);
}

__global__ __launch_bounds__(1024, 4)
void lc_mfma2(const float* __restrict__ zt, const float* __restrict__ zt1,
              float* __restrict__ out) {
    __shared__ SMEM sm;
    char* smb = sm.raw;

    const int tid  = threadIdx.x;
    const int lane = tid & 63;
    const int wid  = tid >> 6;            // 0..15
    const int pw   = wid & 7;             // p-patch id
    const int qh   = wid >> 3;            // q-half (0: qi 0-7, 1: qi 8-15)
    const int py0  = (pw >> 2) * 4;
    const int px0  = (pw & 3) * 4;
    const int nlo  = lane & 3, nhi = (lane >> 2) & 3, oo = lane >> 4;

    const int bid = blockIdx.x;
    const int b   = bid & 7;              // one batch per XCD
    const int t   = bid >> 3;
    const int h0  = (t >> 3) * 8;
    const int w0  = (t & 7) * PW;

    // ---- staging unit descriptors (2 slots/thread) ----
    const float* usrc[2];
    int udst[2], usel[2];
    bool uval[2], uact[2];
#pragma unroll
    for (int s = 0; s < 2; ++s) {
        const int u = tid + s * 1024;
        const bool actB = u < NBU;
        const bool actA = (u >= NBU) && (u < NBU + NAU);
        uact[s] = actB || actA;
        int dst = 0, sel = 0;
        bool val = false;
        const float* src = zt1;
        if (actA) {
            const int u2 = u - NBU;
            const int oct = u2 >> 6, pp = u2 & 63;
            const int py = pp >> 3, pxp = pp & 7;
            dst = (py*16 + pxp*2) * PIXB + oct*16;
            sel = 1; val = true;
            src = zt + (((size_t)(b*CC + oct*8) * HH + (h0 + py)) * WW + (w0 + pxp*2));
        } else if (actB) {
            const int oct = u / 280, pp = u % 280;
            const int qy = pp / 14, qxp = pp % 14;
            const int gy = h0 + qy - 6, gx = w0 + qxp*2 - 6;
            val = (gy >= 0) && (gy < HH) && (gx >= 0) && (gx < WW);
            dst = (qy*QWD + qxp*2) * PIXB + oct*16;
            sel = 0;
            src = zt1 + (((size_t)(b*CC + oct*8) * HH + (val ? gy : 0)) * WW + (val ? gx : 0));
        }
        uval[s] = val; udst[s] = dst; usel[s] = sel; usrc[s] = src;
    }

    // ---- fragment lane offsets ----
    const int laneBoff = ((py0 + nhi)*QWD + (px0 + nlo))*PIXB + oo*16 + qh*17920;
    const int laneAoff = 2*BBUF + ((py0 + nhi)*PW + (px0 + nlo))*PIXB + oo*16;

    f32x4 acc[8];
#pragma unroll
    for (int j = 0; j < 8; ++j) acc[j] = (f32x4){0.f, 0.f, 0.f, 0.f};

    float pfx[2][8], pfy[2][8];

#define STAGE_LOAD(KC)                                                        \
    _Pragma("unroll")                                                         \
    for (int s = 0; s < 2; ++s) {                                             \
        if (uact[s]) {                                                        \
            const float* p = usrc[s] + (size_t)(KC) * CHUNK_ADV;              \
            const bool v = uval[s];                                           \
            _Pragma("unroll")                                                 \
            for (int j = 0; j < 8; ++j) {                                     \
                float2 d = v ? *(const float2*)(p + j*CHPLANE)                \
                             : make_float2(0.f, 0.f);                         \
                pfx[s][j] = d.x; pfy[s][j] = d.y;                             \
            }                                                                 \
        }                                                                     \
    }

#define STAGE_WRITE(PAR)                                                      \
    _Pragma("unroll")                                                         \
    for (int s = 0; s < 2; ++s) {                                             \
        if (uact[s]) {                                                        \
            const int base = usel[s] ? (2*BBUF + (PAR)*ABUF) : ((PAR)*BBUF);  \
            uint4 q0, q1;                                                     \
            q0.x = pk2(pfx[s][0], pfx[s][1]); q0.y = pk2(pfx[s][2], pfx[s][3]);\
            q0.z = pk2(pfx[s][4], pfx[s][5]); q0.w = pk2(pfx[s][6], pfx[s][7]);\
            q1.x = pk2(pfy[s][0], pfy[s][1]); q1.y = pk2(pfy[s][2], pfy[s][3]);\
            q1.z = pk2(pfy[s][4], pfy[s][5]); q1.w = pk2(pfy[s][6], pfy[s][7]);\
            *(uint4*)(smb + base + udst[s]) = q0;                             \
            *(uint4*)(smb + base + udst[s] + PIXB) = q1;                      \
        }                                                                     \
    }

    // prologue: stage chunk 0 into parity 0
    STAGE_LOAD(0)
    STAGE_WRITE(0)
    __syncthreads();

#pragma unroll
    for (int kc = 0; kc < 8; ++kc) {
        if (kc + 1 < 8) { STAGE_LOAD(kc + 1) }

        const char* bbase = smb + (kc & 1)*BBUF + laneBoff;
        const char* abase = smb + (kc & 1)*ABUF + laneAoff;
        const bf16x8 af = *(const bf16x8*)abase;
#pragma unroll
        for (int j = 0; j < 8; ++j) {
            const int imm = (j >> 2)*8960 + (j & 3)*320;   // (qi>>2)*4 rows, (qi&3)*4 cols
            const bf16x8 bfr = *(const bf16x8*)(bbase + imm);
            acc[j] = __builtin_amdgcn_mfma_f32_16x16x32_bf16(af, bfr, acc[j], 0, 0, 0);
        }

        if (kc + 1 < 8) { STAGE_WRITE((kc + 1) & 1) }
        __syncthreads();
    }

    // ---- epilogue: stage through LDS for coalesced stores ----
    // C/D: n = lane&15 (q-pixel), m = oo*4 + r -> py=py0+oo, px=px0+r
    const int psb = (py0 + oo)*PW + px0;
#pragma unroll 1
    for (int pass = 0; pass < 2; ++pass) {
        const int kb = pass * KHALF;
        const int nk = pass ? (NT - KHALF) : KHALF;   // 85 / 84
#pragma unroll
        for (int jj = 0; jj < 8; ++jj) {
            const int qi = qh*8 + jj;
            const int di = 4*(qi >> 2) + nhi - oo;
            const bool diok = (unsigned)di <= 12u;
            const int dib = di * 13;
#pragma unroll
            for (int r = 0; r < 4; ++r) {
                const int dj = 4*(qi & 3) + nlo - r;
                const int k  = dib + dj;
                if (diok && (unsigned)dj <= 12u && k >= kb && k < kb + nk)
                    sm.outb[(k - kb)*OSTRIDE + psb + r] = acc[jj][r] * 0.0625f;
            }
        }
        __syncthreads();
        const int total4 = nk * 32;
        for (int i = tid; i < total4; i += 1024) {
            const int row = i >> 5, j = i & 31;
            const float4 val = *(const float4*)&sm.outb[row*OSTRIDE + j*4];
            float* dst = out + (((size_t)(b*NT + kb + row)*HH + h0 + (j >> 2))*WW
                                + w0 + (j & 3)*4);
            *(float4*)dst = val;
        }
        __syncthreads();
    }
}

extern "C" void kernel_launch(void* const* d_in, const int* in_sizes, int n_in,
                              void* d_out, int out_size, void* d_ws, size_t ws_size,
                              hipStream_t stream) {
    const float* zt  = (const float*)d_in[0];
    const float* zt1 = (const float*)d_in[1];
    float* out = (float*)d_out;
    lc_mfma2<<<dim3(1024), dim3(1024), 0, stream>>>(zt, zt1, out);
}

// Round 4
// 149.958 us; speedup vs baseline: 1.7040x; 1.7040x over previous
//
#include <hip/hip_runtime.h>
#include <hip/hip_bf16.h>

// LocalCorrelation via MFMA, round 4: global_load_lds staging (no register
// round-trip -> loads can't be sunk by regalloc), in-LDS fp32->bf16 transpose
// pack phase, then 16x16x32 bf16 MFMA with R2/R3-verified fragment/epilogue
// mappings. Block = 8h x 16w p-region, 1024 thr = 16 waves (8 p-patches x 2
// q-halves, 8 frags each). Per 32-ch pair: 2x 16-ch half-chunks.
// Pipeline per pair: pack(raw0)+pack(raw1) -> BAR -> issue gloads(next pair,
// fly across MFMA) -> MFMA -> BAR.
// LDS: raw dbuf 2x48KB (linear, gload dest) + bf16 frag 43KB (XOR-swizzled
// via pack writes; rule-21: swizzle on write+read sides, raw dest linear).

#define HH 128
#define WW 128
#define CC 256
#define NT 169
#define PW 16
#define QW 28
#define KHALF 85
#define OSTRIDE 132
#define RAWBUF 49152            // 40960 B-raw + 8192 A-raw per buffer
#define FRAGB 98304             // bf16 frag region base (byte)
#define FRAGA 134144            // = FRAGB + 560*64
#define SMTOT 142336
#define CHADV (16*16384)        // floats to advance per 16-ch half-chunk

typedef __attribute__((ext_vector_type(8))) short bf16x8;
typedef __attribute__((ext_vector_type(4))) float f32x4;

union SMEM {
    char raw[SMTOT];
    float outb[KHALF*OSTRIDE];
};

static __device__ __forceinline__ unsigned pk2(float a, float b) {
    unsigned x = __bfloat16_as_ushort(__float2bfloat16(a));
    unsigned y = __bfloat16_as_ushort(__float2bfloat16(b));
    return x | (y << 16);
}

__global__ __launch_bounds__(1024)
void lc_mfma3(const float* __restrict__ zt, const float* __restrict__ zt1,
              float* __restrict__ out) {
    __shared__ SMEM sm;
    char* smb = sm.raw;

    const int tid  = threadIdx.x;
    const int lane = tid & 63;
    const int wid  = tid >> 6;

    const int bid = blockIdx.x;
    const int b   = bid & 7;              // one batch per XCD
    const int t   = bid >> 3;
    const int h0  = (t >> 3) * 8;
    const int w0  = (t & 7) * 16;

    // ---- gload descriptors: 3 16B units/thread (3072 units total) ----
    // raw B layout: unit u = (ch*20+qy)*8 + part : 32-float row from gx=w0-8
    // raw A layout: unit 2560 + (ch*8+py)*4 + part : 16-float row from w0
    const float* gsrc[3];
    int glds[3];
#pragma unroll
    for (int j = 0; j < 3; ++j) {
        const int u = wid*192 + j*64 + lane;
        const float* s;
        if (u < 2560) {
            const int part = u & 7, tt = u >> 3;
            const int ch = tt / 20, qy = tt - ch*20;
            int gy = h0 + qy - 6; gy = gy < 0 ? 0 : (gy > 127 ? 127 : gy);
            int gx = w0 - 8 + part*4; gx = gx < 0 ? 0 : (gx > 124 ? 124 : gx);
            s = zt1 + (((b*CC + ch)*HH + gy)*WW + gx);   // clamped; masked at pack
        } else {
            const int v = u - 2560;
            const int part = v & 3, tt = v >> 2;
            const int ch = tt >> 3, py = tt & 7;
            s = zt + (((b*CC + ch)*HH + h0 + py)*WW + w0 + part*4);
        }
        gsrc[j] = s;
        glds[j] = (wid*192 + j*64)*16;    // wave-uniform LDS base
    }

#define GISSUE(BUFOFF) { _Pragma("unroll")                                     \
    for (int j = 0; j < 3; ++j) {                                              \
        __builtin_amdgcn_global_load_lds(                                      \
            (const __attribute__((address_space(1))) void*)gsrc[j],            \
            (__attribute__((address_space(3))) void*)(smb + (BUFOFF) + glds[j]),\
            16, 0, 0);                                                         \
        gsrc[j] += CHADV; } }

    // ---- pack descriptors: 688 units (2 pixels x 1 ch-octet each) ----
    const bool pactive = tid < 688;
    int rbase = 0, estride = 0, wa0 = 0, wa1 = 0;
    bool m0 = false, m1 = false;
    if (pactive) {
        const int g = tid >> 1, o = tid & 1;
        if (tid < 560) {                       // B: 280 pixel-pairs x 2 octets
            const int qy = g / 14, qx0 = (g % 14)*2;
            const int gy = h0 + qy - 6;
            const int gx0 = w0 - 6 + qx0;
            const bool yok = (gy >= 0) && (gy < HH);
            m0 = yok && (gx0 >= 0) && (gx0 < WW);
            m1 = yok && (gx0 + 1 >= 0) && (gx0 + 1 < WW);
            rbase = o*8*640 + qy*32 + qx0 + 2;   // dwords; +e*640 per channel
            estride = 640;
            const int fp = qy*QW + qx0;
            wa0 = FRAGB + fp*64 + ((o ^ ((qx0+qy)&3)))*16;
            wa1 = FRAGB + (fp+1)*64 + ((o ^ ((qx0+1+qy)&3)))*16;
        } else {                               // A: 64 pixel-pairs x 2 octets
            const int g2 = g - 280;
            const int py = g2 >> 3, px0 = (g2 & 7)*2;
            m0 = m1 = true;
            rbase = 10240 + o*8*128 + py*16 + px0;
            estride = 128;
            const int fp = py*16 + px0;
            wa0 = FRAGA + fp*64 + ((o ^ ((px0+py)&3)))*16;
            wa1 = FRAGA + (fp+1)*64 + ((o ^ ((px0+1+py)&3)))*16;
        }
    }

#define PACK(RAWOFF, PXOR) if (pactive) {                                      \
    float2 in[8];                                                              \
    _Pragma("unroll")                                                          \
    for (int e = 0; e < 8; ++e)                                                \
        in[e] = *(const float2*)(smb + (RAWOFF) + (rbase + e*estride)*4);      \
    const float z = 0.f;                                                       \
    uint4 q0, q1;                                                              \
    q0.x = pk2(m0?in[0].x:z, m0?in[1].x:z); q0.y = pk2(m0?in[2].x:z, m0?in[3].x:z); \
    q0.z = pk2(m0?in[4].x:z, m0?in[5].x:z); q0.w = pk2(m0?in[6].x:z, m0?in[7].x:z); \
    q1.x = pk2(m1?in[0].y:z, m1?in[1].y:z); q1.y = pk2(m1?in[2].y:z, m1?in[3].y:z); \
    q1.z = pk2(m1?in[4].y:z, m1?in[5].y:z); q1.w = pk2(m1?in[6].y:z, m1?in[7].y:z); \
    *(uint4*)(smb + (wa0 ^ (PXOR))) = q0;                                      \
    *(uint4*)(smb + (wa1 ^ (PXOR))) = q1;                                      \
}

    // ---- MFMA descriptors (R2/R3-verified geometry) ----
    const int pw = wid & 7, qh = wid >> 3;
    const int py0 = (pw >> 2)*4, px0w = (pw & 3)*4;
    const int nlo = lane & 3, nhi = (lane >> 2) & 3, oo = lane >> 4;
    int aoff, boff[8];
    {
        const int pA = py0 + nhi, pxA = px0w + nlo;
        aoff = FRAGA + (pA*16 + pxA)*64 + ((oo ^ ((pxA + pA)&3)))*16;
#pragma unroll
        for (int jj = 0; jj < 8; ++jj) {
            const int qi = qh*8 + jj;
            const int qyL = py0 + (qi >> 2)*4 + nhi;
            const int qxL = px0w + (qi & 3)*4 + nlo;
            boff[jj] = FRAGB + (qyL*QW + qxL)*64 + ((oo ^ ((qxL+qyL)&3)))*16;
        }
    }
    f32x4 acc[8];
#pragma unroll
    for (int j = 0; j < 8; ++j) acc[j] = (f32x4){0.f, 0.f, 0.f, 0.f};

    // ---- main pipeline ----
    GISSUE(0)          // hc0 -> raw0
    GISSUE(RAWBUF)     // hc1 -> raw1
    __syncthreads();   // drains vmcnt: raw0/raw1 ready

#pragma unroll 1
    for (int pr = 0; pr < 8; ++pr) {
        PACK(0, 0)          // even half-chunk -> frag parts 0-1
        PACK(RAWBUF, 32)    // odd half-chunk  -> frag parts 2-3
        __syncthreads();    // frag complete; raw bufs free
        if (pr < 7) { GISSUE(0) GISSUE(RAWBUF) }   // fly across MFMA phase
        const bf16x8 af = *(const bf16x8*)(smb + aoff);
#pragma unroll
        for (int jj = 0; jj < 8; ++jj) {
            const bf16x8 bfr = *(const bf16x8*)(smb + boff[jj]);
            acc[jj] = __builtin_amdgcn_mfma_f32_16x16x32_bf16(af, bfr, acc[jj], 0, 0, 0);
        }
        __syncthreads();    // MFMA frag reads done (+ drains gloads)
    }

    // ---- epilogue (R3-verified) ----
    const int psb = (py0 + oo)*PW + px0w;
#pragma unroll 1
    for (int pass = 0; pass < 2; ++pass) {
        const int kb = pass * KHALF;
        const int nk = pass ? (NT - KHALF) : KHALF;   // 85 / 84
#pragma unroll
        for (int jj = 0; jj < 8; ++jj) {
            const int qi = qh*8 + jj;
            const int di = 4*(qi >> 2) + nhi - oo;
            const bool diok = (unsigned)di <= 12u;
            const int dib = di * 13;
#pragma unroll
            for (int r = 0; r < 4; ++r) {
                const int dj = 4*(qi & 3) + nlo - r;
                const int k  = dib + dj;
                if (diok && (unsigned)dj <= 12u && k >= kb && k < kb + nk)
                    sm.outb[(k - kb)*OSTRIDE + psb + r] = acc[jj][r] * 0.0625f;
            }
        }
        __syncthreads();
        const int total4 = nk * 32;
        for (int i = tid; i < total4; i += 1024) {
            const int row = i >> 5, j = i & 31;
            const float4 val = *(const float4*)&sm.outb[row*OSTRIDE + j*4];
            float* dst = out + (((size_t)(b*NT + kb + row)*HH + h0 + (j >> 2))*WW
                                + w0 + (j & 3)*4);
            *(float4*)dst = val;
        }
        __syncthreads();
    }
}

extern "C" void kernel_launch(void* const* d_in, const int* in_sizes, int n_in,
                              void* d_out, int out_size, void* d_ws, size_t ws_size,
                              hipStream_t stream) {
    const float* zt  = (const float*)d_in[0];
    const float* zt1 = (const float*)d_in[1];
    float* out = (float*)d_out;
    lc_mfma3<<<dim3(1024), dim3(1024), 0, stream>>>(zt, zt1, out);
}